// Round 14
// baseline (1606.327 us; speedup 1.0000x reference)
//
#include <hip/hip_runtime.h>

#define BATCH 32
#define NN0   20480

typedef __attribute__((ext_vector_type(8))) short short8v;
typedef __attribute__((ext_vector_type(4))) float f32x4;

__device__ __forceinline__ float bf2f(unsigned short h) {
    return __uint_as_float(((unsigned int)h) << 16);
}
__device__ __forceinline__ unsigned short f2bf(float x) {
    unsigned int u = __float_as_uint(x);
    u += 0x7fff + ((u >> 16) & 1);   // RNE
    return (unsigned short)(u >> 16);
}
__device__ __forceinline__ unsigned int pk2(float a, float b) {
    return (unsigned int)f2bf(a) | ((unsigned int)f2bf(b) << 16);
}

// ======================= CSR build =======================
__global__ __launch_bounds__(256) void count_kernel(const int* __restrict__ dst, int* __restrict__ cnt, int E) {
    int e = blockIdx.x * 256 + threadIdx.x;
    if (e < E) atomicAdd(&cnt[dst[e]], 1);
}

__global__ __launch_bounds__(256) void scan_kernel(const int* __restrict__ cnt, int* __restrict__ rowptr,
                                                   int* __restrict__ cursor, int n) {
    __shared__ int part[256];
    int tid = threadIdx.x;
    int per = (n + 255) / 256;
    int start = tid * per;
    int end = start + per; if (end > n) end = n; if (start > n) start = n;
    int s = 0;
    for (int i = start; i < end; ++i) s += cnt[i];
    part[tid] = s;
    __syncthreads();
    for (int off = 1; off < 256; off <<= 1) {
        int v = (tid >= off) ? part[tid - off] : 0;
        __syncthreads();
        part[tid] += v;
        __syncthreads();
    }
    int base = (tid == 0) ? 0 : part[tid - 1];
    for (int i = start; i < end; ++i) {
        rowptr[i] = base; cursor[i] = base;
        base += cnt[i];
    }
    if (tid == 255) rowptr[n] = base;
}

__global__ __launch_bounds__(256) void scatter_kernel(const int* __restrict__ src, const int* __restrict__ dst,
                                                      const float* __restrict__ nrm, int* __restrict__ cursor,
                                                      int* __restrict__ esrc, float* __restrict__ ewt,
                                                      int* __restrict__ eid, int E) {
    int e = blockIdx.x * 256 + threadIdx.x;
    if (e >= E) return;
    int p = atomicAdd(&cursor[dst[e]], 1);
    esrc[p] = src[e]; ewt[p] = nrm[e]; eid[p] = e;
}

__global__ __launch_bounds__(256) void sortrows_kernel(const int* __restrict__ rowptr, int* __restrict__ esrc,
                                                       float* __restrict__ ewt, int* __restrict__ eid, int N) {
    int m = blockIdx.x * 256 + threadIdx.x;
    if (m >= N) return;
    int a = rowptr[m], b = rowptr[m + 1];
    for (int i = a + 1; i < b; ++i) {
        int ke = eid[i]; int ks = esrc[i]; float kw = ewt[i];
        int j = i - 1;
        while (j >= a && eid[j] > ke) { eid[j+1]=eid[j]; esrc[j+1]=esrc[j]; ewt[j+1]=ewt[j]; --j; }
        eid[j+1] = ke; esrc[j+1] = ks; ewt[j+1] = kw;
    }
}

// ======================= converts =======================
__global__ __launch_bounds__(256) void convert_flat(const float* __restrict__ in, unsigned short* __restrict__ out,
                                                    size_t n4) {
    for (size_t i = blockIdx.x * 256 + threadIdx.x; i < n4; i += (size_t)gridDim.x * 256) {
        float4 v = reinterpret_cast<const float4*>(in)[i];
        ushort4 o;
        o.x = f2bf(v.x); o.y = f2bf(v.y); o.z = f2bf(v.z); o.w = f2bf(v.w);
        reinterpret_cast<ushort4*>(out)[i] = o;
    }
}

// x fp32 [b*NN0+m][3] -> bf16 node-major [m][b*3+f] (96 cols), LDS transpose per 32-m tile
__global__ __launch_bounds__(256) void xcopy_T(const float* __restrict__ x, unsigned short* __restrict__ out) {
    __shared__ unsigned short sh[32 * 96];
    const int m0 = blockIdx.x * 32;
    const int tid = threadIdx.x;
    const int b = tid >> 3, mi = tid & 7;
#pragma unroll
    for (int ii = 0; ii < 4; ++ii) {
        int mm = mi + ii * 8;
        const float* p = x + ((size_t)b * NN0 + m0 + mm) * 3;
        sh[mm * 96 + b * 3 + 0] = f2bf(p[0]);
        sh[mm * 96 + b * 3 + 1] = f2bf(p[1]);
        sh[mm * 96 + b * 3 + 2] = f2bf(p[2]);
    }
    __syncthreads();
    unsigned int* dst = (unsigned int*)(out + (size_t)m0 * 96);
    const unsigned int* srcp = (const unsigned int*)sh;
    for (int i = tid; i < 32 * 48; i += 256) dst[i] = srcp[i];
}

// ======================= sparse props (bf16) =======================
// half-column pass: 64 lanes x 4 cols = 256 cols per dispatch (cbase = 0 or 256).
__global__ __launch_bounds__(256) void sparse_prop16h(const int* __restrict__ rowptr, const int* __restrict__ esrc,
                                                      const float* __restrict__ ewt,
                                                      const unsigned short* __restrict__ Tin,
                                                      const unsigned short* __restrict__ Tprev,
                                                      unsigned short* __restrict__ Tout, float s, float t,
                                                      int cbase) {
    int g = blockIdx.x * 256 + threadIdx.x;
    int m = g >> 6, lane = g & 63;
    const int c0 = cbase + lane * 4;
    int e0 = rowptr[m], e1 = rowptr[m + 1];
    float a0 = 0.f, a1 = 0.f, a2 = 0.f, a3 = 0.f;
    for (int e = e0; e < e1; ++e) {
        float w = ewt[e];
        uint2 v = *reinterpret_cast<const uint2*>(Tin + (size_t)esrc[e] * 512 + c0);
        a0 += w * bf2f((unsigned short)(v.x & 0xffff));
        a1 += w * bf2f((unsigned short)(v.x >> 16));
        a2 += w * bf2f((unsigned short)(v.y & 0xffff));
        a3 += w * bf2f((unsigned short)(v.y >> 16));
    }
    float r0 = s * a0, r1 = s * a1, r2 = s * a2, r3 = s * a3;
    if (Tprev) {
        uint2 pv = *reinterpret_cast<const uint2*>(Tprev + (size_t)m * 512 + c0);
        r0 += t * bf2f((unsigned short)(pv.x & 0xffff));
        r1 += t * bf2f((unsigned short)(pv.x >> 16));
        r2 += t * bf2f((unsigned short)(pv.y & 0xffff));
        r3 += t * bf2f((unsigned short)(pv.y >> 16));
    }
    uint2 ov;
    ov.x = pk2(r0, r1); ov.y = pk2(r2, r3);
    *reinterpret_cast<uint2*>(Tout + (size_t)m * 512 + c0) = ov;
}

__global__ __launch_bounds__(256) void sparse_prop3(const int* __restrict__ rowptr, const int* __restrict__ esrc,
                                                    const float* __restrict__ ewt,
                                                    const unsigned short* __restrict__ Tin,
                                                    const unsigned short* __restrict__ Tprev,
                                                    unsigned short* __restrict__ Tout, float s, float t) {
    int g = blockIdx.x * 256 + threadIdx.x;
    int m = g / 96, c = g - m * 96;
    int e0 = rowptr[m], e1 = rowptr[m + 1];
    float acc = 0.f;
    for (int e = e0; e < e1; ++e)
        acc += ewt[e] * bf2f(Tin[(size_t)esrc[e] * 96 + c]);
    float v = s * acc;
    if (Tprev) v += t * bf2f(Tprev[(size_t)m * 96 + c]);
    Tout[(size_t)m * 96 + c] = f2bf(v);
}

// ======================= fused sparse epilogue -> bf16 node-major =======================
template <int FIN, int FOUT>
__global__ __launch_bounds__(256) void sparse_epi(const unsigned short* __restrict__ S, size_t slot,
                                                  const float* __restrict__ W, const float* __restrict__ bias,
                                                  unsigned short* __restrict__ out, int relu) {
    __shared__ float Ws[6 * FIN * FOUT];
    for (int i = threadIdx.x; i < 6 * FIN * FOUT; i += 256) Ws[i] = W[i];
    __syncthreads();
    int g = blockIdx.x * 256 + threadIdx.x;   // g = m*32 + b
    int m = g >> 5, b = g & 31;
    float oa[FOUT];
#pragma unroll
    for (int o = 0; o < FOUT; ++o) oa[o] = bias ? bias[o] : 0.f;
    for (int k = 0; k < 6; ++k) {
        const unsigned short* p = S + (size_t)k * slot + (size_t)m * (32 * FIN) + b * FIN;
        float xv[FIN];
        if constexpr (FIN == 16) {
            short8v v0 = *reinterpret_cast<const short8v*>(p);
            short8v v1 = *reinterpret_cast<const short8v*>(p + 8);
#pragma unroll
            for (int f = 0; f < 8; ++f) { xv[f] = bf2f((unsigned short)v0[f]); xv[f + 8] = bf2f((unsigned short)v1[f]); }
        } else {
#pragma unroll
            for (int f = 0; f < FIN; ++f) xv[f] = bf2f(p[f]);
        }
#pragma unroll
        for (int f = 0; f < FIN; ++f)
#pragma unroll
            for (int o = 0; o < FOUT; ++o) oa[o] += xv[f] * Ws[(k * FIN + f) * FOUT + o];
    }
    unsigned short* orow = out + (size_t)m * (32 * FOUT) + b * FOUT;
    unsigned int u[FOUT / 2];
#pragma unroll
    for (int o = 0; o < FOUT / 2; ++o) {
        float a = oa[2 * o], c = oa[2 * o + 1];
        if (relu) { a = fmaxf(a, 0.f); c = fmaxf(c, 0.f); }
        u[o] = pk2(a, c);
    }
#pragma unroll
    for (int q = 0; q < FOUT / 8; ++q)
        reinterpret_cast<uint4*>(orow)[q] = make_uint4(u[4 * q], u[4 * q + 1], u[4 * q + 2], u[4 * q + 3]);
}

// final epilogue: FIN=16 -> 3, fp32 d_out at (b*NN0+m)*3, LDS-staged contiguous writes
__global__ __launch_bounds__(256) void sparse_epi_final(const unsigned short* __restrict__ S, size_t slot,
                                                        const float* __restrict__ W, float* __restrict__ dout) {
    __shared__ float Ws[6 * 16 * 3];
    __shared__ float sh[32 * 24];
    for (int i = threadIdx.x; i < 288; i += 256) Ws[i] = W[i];
    __syncthreads();
    const int tid = threadIdx.x;
    const int mm = tid >> 5, b = tid & 31;
    const int m = blockIdx.x * 8 + mm;
    float o0 = 0.f, o1 = 0.f, o2 = 0.f;
    for (int k = 0; k < 6; ++k) {
        const unsigned short* p = S + (size_t)k * slot + (size_t)m * 512 + b * 16;
        short8v v0 = *reinterpret_cast<const short8v*>(p);
        short8v v1 = *reinterpret_cast<const short8v*>(p + 8);
#pragma unroll
        for (int f = 0; f < 16; ++f) {
            float xf = bf2f((unsigned short)(f < 8 ? v0[f] : v1[f - 8]));
            o0 += xf * Ws[(k * 16 + f) * 3 + 0];
            o1 += xf * Ws[(k * 16 + f) * 3 + 1];
            o2 += xf * Ws[(k * 16 + f) * 3 + 2];
        }
    }
    sh[b * 24 + mm * 3 + 0] = o0;
    sh[b * 24 + mm * 3 + 1] = o1;
    sh[b * 24 + mm * 3 + 2] = o2;
    __syncthreads();
    const size_t base = (size_t)blockIdx.x * 24;
    for (int i = tid; i < 768; i += 256) {
        int b2 = i / 24, r = i - b2 * 24;
        dout[(size_t)b2 * (NN0 * 3) + base + r] = sh[i];
    }
}

// ======================= pools =======================
__device__ __forceinline__ float ldv(const float* p) { return *p; }
__device__ __forceinline__ float ldv(const unsigned short* p) { return bf2f(*p); }

template <typename TI>
__global__ __launch_bounds__(256) void pool_cT(const TI* __restrict__ in, const int* __restrict__ idx,
                                               const float* __restrict__ w, unsigned short* __restrict__ out,
                                               int C, int Mnew) {
    __shared__ float tile[32][33];
    const int m0 = blockIdx.x * 32, c0 = blockIdx.y * 32;
    const int tx = threadIdx.x & 31, ty = threadIdx.x >> 5;
#pragma unroll
    for (int i = 0; i < 4; ++i) {
        int mn = m0 + ty + i * 8;
        const int* ir = idx + mn * 3; const float* wr = w + mn * 3;
        float v = wr[0] * ldv(in + (size_t)ir[0] * C + c0 + tx)
                + wr[1] * ldv(in + (size_t)ir[1] * C + c0 + tx)
                + wr[2] * ldv(in + (size_t)ir[2] * C + c0 + tx);
        tile[ty + i * 8][tx] = v;
    }
    __syncthreads();
#pragma unroll
    for (int i = 0; i < 4; ++i) {
        int c = c0 + ty + i * 8;
        out[(size_t)c * Mnew + m0 + tx] = f2bf(tile[tx][ty + i * 8]);
    }
}

__global__ __launch_bounds__(256) void pool_row16(const unsigned short* __restrict__ in, const int* __restrict__ idx,
                                                  const float* __restrict__ w, unsigned short* __restrict__ out) {
    int g = blockIdx.x * 256 + threadIdx.x;
    int m = g >> 6, lane = g & 63;
    const int* ir = idx + m * 3; const float* wr = w + m * 3;
    short8v a = *reinterpret_cast<const short8v*>(in + (size_t)ir[0] * 512 + lane * 8);
    short8v b = *reinterpret_cast<const short8v*>(in + (size_t)ir[1] * 512 + lane * 8);
    short8v c = *reinterpret_cast<const short8v*>(in + (size_t)ir[2] * 512 + lane * 8);
    float r[8];
#pragma unroll
    for (int j = 0; j < 8; ++j)
        r[j] = wr[0] * bf2f((unsigned short)a[j]) + wr[1] * bf2f((unsigned short)b[j]) + wr[2] * bf2f((unsigned short)c[j]);
    uint4 ov;
    ov.x = pk2(r[0], r[1]); ov.y = pk2(r[2], r[3]); ov.z = pk2(r[4], r[5]); ov.w = pk2(r[6], r[7]);
    *reinterpret_cast<uint4*>(out + (size_t)m * 512 + lane * 8) = ov;
}

__global__ __launch_bounds__(256) void pool_f32(const unsigned short* __restrict__ in, const int* __restrict__ idx,
                                                const float* __restrict__ w, float* __restrict__ out) {
    int g = blockIdx.x * 256 + threadIdx.x;   // 80*1024
    int m = g >> 10, c = g & 1023;
    const int* ir = idx + m * 3; const float* wr = w + m * 3;
    out[g] = wr[0] * bf2f(in[(size_t)ir[0] * 1024 + c])
           + wr[1] * bf2f(in[(size_t)ir[1] * 1024 + c])
           + wr[2] * bf2f(in[(size_t)ir[2] * 1024 + c]);
}

// ======================= MFMA prop GEMM, 2-phase double-buffered ==========================
// Tile BM = MF*64 rows x BN = CF*16 cols. SPLIT: writes bf16 partial Pf[z][C][M].
template <int MF, int CF, bool SPLIT>
__global__ __launch_bounds__(256) void gemm_mfma(const unsigned short* __restrict__ Ab,
                                                 const unsigned short* __restrict__ Xb,
                                                 const unsigned short* __restrict__ Pb,
                                                 unsigned short* __restrict__ Ob,
                                                 unsigned short* __restrict__ Pf,
                                                 int Mn, int KC, float s, float t) {
    constexpr int BM = MF * 64;
    constexpr int BN = CF * 16;
    constexpr int ABYTES = BM * 64 * 2;
    constexpr int XBYTES = BN * 64 * 2;
    constexpr int SEGA = ABYTES / 4096;
    constexpr int SEGX = XBYTES / 4096;
    __shared__ unsigned short As[2][BM * 64];
    __shared__ unsigned short Xs[2][BN * 64];
    const int tid = threadIdx.x;
    const int lane = tid & 63, wid = tid >> 6;
    int lin = blockIdx.y * gridDim.x + blockIdx.x;
    int nwg = gridDim.x * gridDim.y;
    int lin2 = (lin & 7) * (nwg >> 3) + (lin >> 3);
    int by = lin2 / gridDim.x, bx = lin2 - by * gridDim.x;
    const int bm = by * BM, bc = bx * BN;
    const int kbase = SPLIT ? blockIdx.z * KC : 0;
    const int NT = KC / 64;

    const unsigned short* gAsrc[SEGA];
    unsigned int ldsAoff[SEGA];
#pragma unroll
    for (int i = 0; i < SEGA; ++i) {
        int o = (wid * SEGA + i) * 1024 + lane * 16;
        int row = o >> 7;
        int colb = (o & 127) ^ ((row & 7) << 4);
        gAsrc[i] = Ab + (size_t)(bm + row) * Mn + kbase + (colb >> 1);
        ldsAoff[i] = (unsigned int)(wid * SEGA + i) * 1024;
    }
    const unsigned short* gXsrc[SEGX];
    unsigned int ldsXoff[SEGX];
#pragma unroll
    for (int i = 0; i < SEGX; ++i) {
        int o = (wid * SEGX + i) * 1024 + lane * 16;
        int row = o >> 7;
        int colb = (o & 127) ^ ((row & 7) << 4);
        gXsrc[i] = Xb + (size_t)(bc + row) * Mn + kbase + (colb >> 1);
        ldsXoff[i] = (unsigned int)(wid * SEGX + i) * 1024;
    }

    auto STAGE = [&](int buf, int ko) {
#pragma unroll
        for (int i = 0; i < SEGA; ++i)
            __builtin_amdgcn_global_load_lds((const __attribute__((address_space(1))) void*)(gAsrc[i] + ko),
                                             (__attribute__((address_space(3))) void*)((char*)As + buf * ABYTES + ldsAoff[i]),
                                             16, 0, 0);
#pragma unroll
        for (int i = 0; i < SEGX; ++i)
            __builtin_amdgcn_global_load_lds((const __attribute__((address_space(1))) void*)(gXsrc[i] + ko),
                                             (__attribute__((address_space(3))) void*)((char*)Xs + buf * XBYTES + ldsXoff[i]),
                                             16, 0, 0);
    };

    f32x4 acc[MF][CF] = {};

    STAGE(0, 0);
    __syncthreads();
    for (int tt = 0; tt < NT; ++tt) {
        const int cur = tt & 1;
        if (tt + 1 < NT) STAGE(cur ^ 1, (tt + 1) * 64);
        const char* Ac = (const char*)As + cur * ABYTES;
        const char* Xc = (const char*)Xs + cur * XBYTES;
#pragma unroll
        for (int kk = 0; kk < 2; ++kk) {
            short8v a[MF], b[CF];
#pragma unroll
            for (int mf = 0; mf < MF; ++mf) {
                int r = wid * (MF * 16) + mf * 16 + (lane & 15);
                int cb = kk * 64 + ((lane >> 4) * 16);
                int addr = r * 128 + (cb ^ ((r & 7) << 4));
                a[mf] = *reinterpret_cast<const short8v*>(Ac + addr);
            }
#pragma unroll
            for (int cf = 0; cf < CF; ++cf) {
                int r = cf * 16 + (lane & 15);
                int cb = kk * 64 + ((lane >> 4) * 16);
                int addr = r * 128 + (cb ^ ((r & 7) << 4));
                b[cf] = *reinterpret_cast<const short8v*>(Xc + addr);
            }
#pragma unroll
            for (int mf = 0; mf < MF; ++mf)
#pragma unroll
                for (int cf = 0; cf < CF; ++cf)
                    acc[mf][cf] = __builtin_amdgcn_mfma_f32_16x16x32_bf16(a[mf], b[cf], acc[mf][cf], 0, 0, 0);
        }
        __syncthreads();
    }

#pragma unroll
    for (int mf = 0; mf < MF; ++mf) {
        int m0 = bm + wid * (MF * 16) + mf * 16 + ((lane >> 4) * 4);
#pragma unroll
        for (int cf = 0; cf < CF; ++cf) {
            int c = bc + cf * 16 + (lane & 15);
            size_t base = (size_t)c * Mn + m0;
            if constexpr (SPLIT) {
                size_t zbase = (size_t)blockIdx.z * (size_t)(gridDim.x * BN) * (size_t)Mn;
                uint2 ov;
                ov.x = pk2(acc[mf][cf][0], acc[mf][cf][1]);
                ov.y = pk2(acc[mf][cf][2], acc[mf][cf][3]);
                *reinterpret_cast<uint2*>(Pf + zbase + base) = ov;
            } else {
                float v0 = s * acc[mf][cf][0], v1 = s * acc[mf][cf][1];
                float v2 = s * acc[mf][cf][2], v3 = s * acc[mf][cf][3];
                if (Pb) {
                    uint2 pv = *reinterpret_cast<const uint2*>(Pb + base);
                    v0 += t * bf2f((unsigned short)(pv.x & 0xffff));
                    v1 += t * bf2f((unsigned short)(pv.x >> 16));
                    v2 += t * bf2f((unsigned short)(pv.y & 0xffff));
                    v3 += t * bf2f((unsigned short)(pv.y >> 16));
                }
                uint2 ov;
                ov.x = pk2(v0, v1); ov.y = pk2(v2, v3);
                *reinterpret_cast<uint2*>(Ob + base) = ov;
            }
        }
    }
}

// split-K reduce (bf16 partials): Out[g] = bf16( s*sum_ks Pf[ks][g] + t*Prev[g] ), 4 elems/thread
__global__ __launch_bounds__(256) void sk_reduce(const unsigned short* __restrict__ Pf,
                                                 const unsigned short* __restrict__ Prev,
                                                 unsigned short* __restrict__ Out,
                                                 int n4, int KS, float s, float t) {
    int g = blockIdx.x * 256 + threadIdx.x;
    if (g >= n4) return;
    float v0 = 0.f, v1 = 0.f, v2 = 0.f, v3 = 0.f;
    for (int ks = 0; ks < KS; ++ks) {
        uint2 pv = reinterpret_cast<const uint2*>(Pf)[(size_t)ks * n4 + g];
        v0 += bf2f((unsigned short)(pv.x & 0xffff));
        v1 += bf2f((unsigned short)(pv.x >> 16));
        v2 += bf2f((unsigned short)(pv.y & 0xffff));
        v3 += bf2f((unsigned short)(pv.y >> 16));
    }
    v0 *= s; v1 *= s; v2 *= s; v3 *= s;
    if (Prev) {
        uint2 pv = reinterpret_cast<const uint2*>(Prev)[g];
        v0 += t * bf2f((unsigned short)(pv.x & 0xffff));
        v1 += t * bf2f((unsigned short)(pv.x >> 16));
        v2 += t * bf2f((unsigned short)(pv.y & 0xffff));
        v3 += t * bf2f((unsigned short)(pv.y >> 16));
    }
    uint2 ov;
    ov.x = pk2(v0, v1); ov.y = pk2(v2, v3);
    reinterpret_cast<uint2*>(Out)[g] = ov;
}

// ======================= dense fused epilogue -> bf16 [m][32*FOUT] =======================
template <int FIN, int FOUT>
__global__ __launch_bounds__(256) void epi_layer(const unsigned short* __restrict__ Tb, size_t tslot,
                                                 const float* __restrict__ W, const float* __restrict__ bias,
                                                 unsigned short* __restrict__ out, int M) {
    __shared__ float Ws[6 * FIN * FOUT];
    for (int i = threadIdx.x; i < 6 * FIN * FOUT; i += 256) Ws[i] = W[i];
    __syncthreads();
    int g = blockIdx.x * 256 + threadIdx.x;   // g = b*M + m
    int b = g / M, m = g - b * M;
    float oa[FOUT];
#pragma unroll
    for (int o = 0; o < FOUT; ++o) oa[o] = bias[o];
    for (int k = 0; k < 6; ++k) {
        const unsigned short* Tk = Tb + (size_t)k * tslot + (size_t)b * FIN * M + m;
#pragma unroll
        for (int f = 0; f < FIN; ++f) {
            float xf = bf2f(Tk[(size_t)f * M]);
#pragma unroll
            for (int o = 0; o < FOUT; ++o) oa[o] += xf * Ws[(k * FIN + f) * FOUT + o];
        }
    }
    unsigned short* orow = out + (size_t)m * (32 * FOUT) + b * FOUT;
    unsigned int u[FOUT / 2];
#pragma unroll
    for (int o = 0; o < FOUT / 2; ++o)
        u[o] = pk2(fmaxf(oa[2 * o], 0.f), fmaxf(oa[2 * o + 1], 0.f));
#pragma unroll
    for (int q = 0; q < FOUT / 8; ++q)
        reinterpret_cast<uint4*>(orow)[q] = make_uint4(u[4 * q], u[4 * q + 1], u[4 * q + 2], u[4 * q + 3]);
}

// ======================= FCs =======================
__global__ __launch_bounds__(256) void fc_enc_kernel(const float* __restrict__ h, const float* __restrict__ w,
                                                     const float* __restrict__ bias, float* __restrict__ z) {
    __shared__ float sh[256];
    int b = blockIdx.x, o = threadIdx.x & 63, q = threadIdx.x >> 6;
    float acc = 0.f;
    for (int n = q * 20; n < q * 20 + 20; ++n)
#pragma unroll
        for (int f = 0; f < 32; ++f)
            acc += h[((size_t)n * 32 + b) * 32 + f] * w[(size_t)o * 2560 + n * 32 + f];
    sh[threadIdx.x] = acc;
    __syncthreads();
    if (q == 0) z[b * 64 + o] = fmaxf(sh[o] + sh[64 + o] + sh[128 + o] + sh[192 + o] + bias[o], 0.f);
}

__global__ __launch_bounds__(256) void fc_dec_kernel(const float* __restrict__ z, const float* __restrict__ w,
                                                     const float* __restrict__ bias, float* __restrict__ out) {
    int g = blockIdx.x * 256 + threadIdx.x;   // 80*32*32, layout [n][b*32+f]
    if (g >= 80 * 32 * 32) return;
    int f = g % 32; int b = (g / 32) % 32; int n = g / 1024;
    int j = n * 32 + f;
    float acc = bias[j];
    const float* wr = w + (size_t)j * 64;
    const float* zr = z + b * 64;
#pragma unroll
    for (int o = 0; o < 64; ++o) acc += zr[o] * wr[o];
    out[g] = fmaxf(acc, 0.f);
}

// ======================= host orchestration =======================
extern "C" void kernel_launch(void* const* d_in, const int* in_sizes, int n_in,
                              void* d_out, int out_size, void* d_ws, size_t ws_size,
                              hipStream_t stream) {
    (void)n_in; (void)out_size; (void)ws_size;
    const float* x     = (const float*)d_in[0];
    const int*   ei    = (const int*)d_in[1];
    const float* anorm = (const float*)d_in[2];
    const float* adjs[3] = { (const float*)d_in[4], (const float*)d_in[5], (const float*)d_in[6] };
    const int*   dn_idx[4] = { (const int*)d_in[7],  (const int*)d_in[11], (const int*)d_in[15], (const int*)d_in[19] };
    const float* dn_w[4]   = { (const float*)d_in[8],(const float*)d_in[12],(const float*)d_in[16],(const float*)d_in[20] };
    const int*   up_idx[4] = { (const int*)d_in[9],  (const int*)d_in[13], (const int*)d_in[17], (const int*)d_in[21] };
    const float* up_w[4]   = { (const float*)d_in[10],(const float*)d_in[14],(const float*)d_in[18],(const float*)d_in[22] };
    const float* W_enc[4] = { (const float*)d_in[23], (const float*)d_in[25], (const float*)d_in[27], (const float*)d_in[29] };
    const float* b_enc[4] = { (const float*)d_in[24], (const float*)d_in[26], (const float*)d_in[28], (const float*)d_in[30] };
    const float* W_dec[5] = { (const float*)d_in[31], (const float*)d_in[33], (const float*)d_in[35], (const float*)d_in[37], (const float*)d_in[39] };
    const float* b_dec[4] = { (const float*)d_in[32], (const float*)d_in[34], (const float*)d_in[36], (const float*)d_in[38] };
    const float* enc_w = (const float*)d_in[40];
    const float* enc_b = (const float*)d_in[41];
    const float* dec_w = (const float*)d_in[42];
    const float* dec_b = (const float*)d_in[43];
    const int E = in_sizes[2];

    // ---- workspace layout (live-range aliased) ----
    const size_t SLOT16 = (size_t)NN0 * 512;          // ushort elems, 21 MB
    const size_t SLOT3  = (size_t)NN0 * 96;
    unsigned short* S = (unsigned short*)d_ws;        // sparse slots; also split-K partial region (disjoint in time)
    unsigned short* Pf = (unsigned short*)d_ws;       // bf16 partials during dense layers (<= 21 MB)
    unsigned short* Tb = S + 3 * SLOT16;
    unsigned short* HB = Tb + (size_t)6 * 512 * 5120;
    char* p = (char*)(HB + SLOT16);
    unsigned short* adj1b = (unsigned short*)p; p += (size_t)5120 * 5120 * 2;
    unsigned short* adj2b = (unsigned short*)p; p += (size_t)1280 * 1280 * 2;
    unsigned short* adj3b = (unsigned short*)p; p += (size_t)320 * 320 * 2;
    int* rowptr = (int*)p;  p += (NN0 + 4) * sizeof(int);
    int* cnt    = (int*)p;  p += NN0 * sizeof(int);
    int* cursor = (int*)p;  p += NN0 * sizeof(int);
    int* esrc   = (int*)p;  p += (size_t)E * sizeof(int);
    int* eid    = (int*)p;  p += (size_t)E * sizeof(int);
    float* ewt  = (float*)p; p += (size_t)E * sizeof(float);
    float* lat0 = (float*)p; p += 80 * 1024 * sizeof(float);
    float* zb   = (float*)p; p += 32 * 64 * sizeof(float);
    float* lat1 = (float*)p;

    // ---- CSR build (deterministic via per-row sort by edge id) ----
    hipMemsetAsync(cnt, 0, NN0 * sizeof(int), stream);
    count_kernel<<<(E + 255) / 256, 256, 0, stream>>>(ei + E, cnt, E);
    scan_kernel<<<1, 256, 0, stream>>>(cnt, rowptr, cursor, NN0);
    scatter_kernel<<<(E + 255) / 256, 256, 0, stream>>>(ei, ei + E, anorm, cursor, esrc, ewt, eid, E);
    sortrows_kernel<<<(NN0 + 255) / 256, 256, 0, stream>>>(rowptr, esrc, ewt, eid, NN0);

    // ---- adjacency bf16 conversion ----
    convert_flat<<<2048, 256, 0, stream>>>(adjs[0], adj1b, (size_t)5120 * 5120 / 4);
    convert_flat<<<512, 256, 0, stream>>>(adjs[1], adj2b, (size_t)1280 * 1280 / 4);
    convert_flat<<<64, 256, 0, stream>>>(adjs[2], adj3b, (size_t)320 * 320 / 4);

    // ---- helpers ----
    auto dense_layer = [&](const unsigned short* Ab, int M, int FIN, int FOUT,
                           const float* W, const float* bias, unsigned short* HBout) {
        const int C = 32 * FIN;
        const size_t tslot = (size_t)C * M;
        const int CM4 = (int)(tslot / 4);
        for (int k = 1; k < 6; ++k) {
            const unsigned short* Xin = Tb + (size_t)(k - 1) * tslot;
            const unsigned short* Pv  = (k >= 2) ? Tb + (size_t)(k - 2) * tslot : nullptr;
            unsigned short* Oo = Tb + (size_t)k * tslot;
            float s = (k == 1) ? 1.f : 2.f;
            float t = (k == 1) ? 0.f : -1.f;
            if (M == 5120) {
                dim3 gg(C / 64, M / 128, 4);   // BM=128, BN=64, KS=4, KC=1280, 2-phase LDS dbuf
                gemm_mfma<2, 4, true><<<gg, 256, 0, stream>>>(Ab, Xin, nullptr, nullptr, Pf, M, 1280, s, t);
                sk_reduce<<<(CM4 + 255) / 256, 256, 0, stream>>>(Pf, Pv, Oo, CM4, 4, s, t);
            } else if (M == 1280) {
                dim3 gg(C / 64, M / 64, 4);
                gemm_mfma<1, 4, true><<<gg, 256, 0, stream>>>(Ab, Xin, nullptr, nullptr, Pf, M, 320, s, t);
                sk_reduce<<<(CM4 + 255) / 256, 256, 0, stream>>>(Pf, Pv, Oo, CM4, 4, s, t);
            } else {   // M == 320: small, non-split, latency-floor path
                dim3 gg(C / 64, M / 64, 1);
                gemm_mfma<1, 4, false><<<gg, 256, 0, stream>>>(Ab, Xin, Pv, Oo, nullptr, M, M, s, t);
            }
        }
        int blocks = M * 32 / 256;
        if (FIN == 16 && FOUT == 16)      epi_layer<16, 16><<<blocks, 256, 0, stream>>>(Tb, tslot, W, bias, HBout, M);
        else if (FIN == 16 && FOUT == 32) epi_layer<16, 32><<<blocks, 256, 0, stream>>>(Tb, tslot, W, bias, HBout, M);
        else                              epi_layer<32, 16><<<blocks, 256, 0, stream>>>(Tb, tslot, W, bias, HBout, M);
    };
    auto sparse_layer16 = [&](const float* W, const float* bias, int final_relu, unsigned short* out16) {
        for (int k = 1; k < 6; ++k) {
            const unsigned short* Tin = S + (size_t)(k - 1) * SLOT16;
            const unsigned short* Pv  = (k >= 2) ? S + (size_t)(k - 2) * SLOT16 : nullptr;
            unsigned short* To = S + (size_t)k * SLOT16;
            float sv = (k == 1) ? 1.f : 2.f;
            float tv = (k == 1) ? 0.f : -1.f;
            sparse_prop16h<<<NN0 / 4, 256, 0, stream>>>(rowptr, esrc, ewt, Tin, Pv, To, sv, tv, 0);
            sparse_prop16h<<<NN0 / 4, 256, 0, stream>>>(rowptr, esrc, ewt, Tin, Pv, To, sv, tv, 256);
        }
        if (out16) sparse_epi<16, 16><<<NN0 * 32 / 256, 256, 0, stream>>>(S, SLOT16, W, bias, out16, final_relu);
        else       sparse_epi_final<<<NN0 / 8, 256, 0, stream>>>(S, SLOT16, W, (float*)d_out);
    };

    // ======================= network =======================
    // --- encoder sparse layer (FIN=3) ---
    xcopy_T<<<NN0 / 32, 256, 0, stream>>>(x, S);
    for (int k = 1; k < 6; ++k) {
        const unsigned short* Tin = S + (size_t)(k - 1) * SLOT3;
        const unsigned short* Pv  = (k >= 2) ? S + (size_t)(k - 2) * SLOT3 : nullptr;
        sparse_prop3<<<NN0 * 96 / 256, 256, 0, stream>>>(rowptr, esrc, ewt, Tin, Pv, S + (size_t)k * SLOT3,
                                                         (k == 1) ? 1.f : 2.f, (k == 1) ? 0.f : -1.f);
    }
    sparse_epi<3, 16><<<NN0 * 32 / 256, 256, 0, stream>>>(S, SLOT3, W_enc[0], b_enc[0], HB, 1);
    // --- dense encoder ---
    { dim3 g(5120 / 32, 512 / 32);  pool_cT<unsigned short><<<g, 256, 0, stream>>>(HB, dn_idx[0], dn_w[0], Tb, 512, 5120); }
    dense_layer(adj1b, 5120, 16, 16, W_enc[1], b_enc[1], HB);
    { dim3 g(1280 / 32, 512 / 32);  pool_cT<unsigned short><<<g, 256, 0, stream>>>(HB, dn_idx[1], dn_w[1], Tb, 512, 1280); }
    dense_layer(adj2b, 1280, 16, 16, W_enc[2], b_enc[2], HB);
    { dim3 g(320 / 32, 512 / 32);   pool_cT<unsigned short><<<g, 256, 0, stream>>>(HB, dn_idx[2], dn_w[2], Tb, 512, 320); }
    dense_layer(adj3b, 320, 16, 32, W_enc[3], b_enc[3], HB);
    pool_f32<<<80 * 1024 / 256, 256, 0, stream>>>(HB, dn_idx[3], dn_w[3], lat0);
    fc_enc_kernel<<<32, 256, 0, stream>>>(lat0, enc_w, enc_b, zb);
    // --- decoder ---
    fc_dec_kernel<<<80 * 32 * 32 / 256, 256, 0, stream>>>(zb, dec_w, dec_b, lat1);
    { dim3 g(320 / 32, 1024 / 32);  pool_cT<float><<<g, 256, 0, stream>>>(lat1, up_idx[3], up_w[3], Tb, 1024, 320); }
    dense_layer(adj3b, 320, 32, 16, W_dec[0], b_dec[0], HB);
    { dim3 g(1280 / 32, 512 / 32);  pool_cT<unsigned short><<<g, 256, 0, stream>>>(HB, up_idx[2], up_w[2], Tb, 512, 1280); }
    dense_layer(adj2b, 1280, 16, 16, W_dec[1], b_dec[1], HB);
    { dim3 g(5120 / 32, 512 / 32);  pool_cT<unsigned short><<<g, 256, 0, stream>>>(HB, up_idx[1], up_w[1], Tb, 512, 5120); }
    dense_layer(adj1b, 5120, 16, 16, W_dec[2], b_dec[2], HB);
    pool_row16<<<NN0 / 4, 256, 0, stream>>>(HB, up_idx[0], up_w[0], S);   // -> S slot0
    // --- decoder sparse layers (FIN=16) ---
    sparse_layer16(W_dec[3], b_dec[3], 1, S);          // epi writes slot0 in-place (owner-thread-safe)
    sparse_layer16(W_dec[4], nullptr, 0, nullptr);     // final -> d_out
}

// Round 15
// 1433.984 us; speedup vs baseline: 1.1202x; 1.1202x over previous
//
#include <hip/hip_runtime.h>

#define BATCH 32
#define NN0   20480

typedef __attribute__((ext_vector_type(8))) short short8v;
typedef __attribute__((ext_vector_type(4))) float f32x4;

__device__ __forceinline__ float bf2f(unsigned short h) {
    return __uint_as_float(((unsigned int)h) << 16);
}
__device__ __forceinline__ unsigned short f2bf(float x) {
    unsigned int u = __float_as_uint(x);
    u += 0x7fff + ((u >> 16) & 1);   // RNE
    return (unsigned short)(u >> 16);
}
__device__ __forceinline__ unsigned int pk2(float a, float b) {
    return (unsigned int)f2bf(a) | ((unsigned int)f2bf(b) << 16);
}

// ======================= CSR build =======================
__global__ __launch_bounds__(256) void count_kernel(const int* __restrict__ dst, int* __restrict__ cnt, int E) {
    int e = blockIdx.x * 256 + threadIdx.x;
    if (e < E) atomicAdd(&cnt[dst[e]], 1);
}

__global__ __launch_bounds__(256) void scan_kernel(const int* __restrict__ cnt, int* __restrict__ rowptr,
                                                   int* __restrict__ cursor, int n) {
    __shared__ int part[256];
    int tid = threadIdx.x;
    int per = (n + 255) / 256;
    int start = tid * per;
    int end = start + per; if (end > n) end = n; if (start > n) start = n;
    int s = 0;
    for (int i = start; i < end; ++i) s += cnt[i];
    part[tid] = s;
    __syncthreads();
    for (int off = 1; off < 256; off <<= 1) {
        int v = (tid >= off) ? part[tid - off] : 0;
        __syncthreads();
        part[tid] += v;
        __syncthreads();
    }
    int base = (tid == 0) ? 0 : part[tid - 1];
    for (int i = start; i < end; ++i) {
        rowptr[i] = base; cursor[i] = base;
        base += cnt[i];
    }
    if (tid == 255) rowptr[n] = base;
}

__global__ __launch_bounds__(256) void scatter_kernel(const int* __restrict__ src, const int* __restrict__ dst,
                                                      const float* __restrict__ nrm, int* __restrict__ cursor,
                                                      int* __restrict__ esrc, float* __restrict__ ewt,
                                                      int* __restrict__ eid, int E) {
    int e = blockIdx.x * 256 + threadIdx.x;
    if (e >= E) return;
    int p = atomicAdd(&cursor[dst[e]], 1);
    esrc[p] = src[e]; ewt[p] = nrm[e]; eid[p] = e;
}

__global__ __launch_bounds__(256) void sortrows_kernel(const int* __restrict__ rowptr, int* __restrict__ esrc,
                                                       float* __restrict__ ewt, int* __restrict__ eid, int N) {
    int m = blockIdx.x * 256 + threadIdx.x;
    if (m >= N) return;
    int a = rowptr[m], b = rowptr[m + 1];
    for (int i = a + 1; i < b; ++i) {
        int ke = eid[i]; int ks = esrc[i]; float kw = ewt[i];
        int j = i - 1;
        while (j >= a && eid[j] > ke) { eid[j+1]=eid[j]; esrc[j+1]=esrc[j]; ewt[j+1]=ewt[j]; --j; }
        eid[j+1] = ke; esrc[j+1] = ks; ewt[j+1] = kw;
    }
}

// ======================= converts =======================
__global__ __launch_bounds__(256) void convert_flat(const float* __restrict__ in, unsigned short* __restrict__ out,
                                                    size_t n4) {
    for (size_t i = blockIdx.x * 256 + threadIdx.x; i < n4; i += (size_t)gridDim.x * 256) {
        float4 v = reinterpret_cast<const float4*>(in)[i];
        ushort4 o;
        o.x = f2bf(v.x); o.y = f2bf(v.y); o.z = f2bf(v.z); o.w = f2bf(v.w);
        reinterpret_cast<ushort4*>(out)[i] = o;
    }
}

// x fp32 [b*NN0+m][3] -> bf16 node-major [m][b*3+f] (96 cols), LDS transpose per 32-m tile
__global__ __launch_bounds__(256) void xcopy_T(const float* __restrict__ x, unsigned short* __restrict__ out) {
    __shared__ unsigned short sh[32 * 96];
    const int m0 = blockIdx.x * 32;
    const int tid = threadIdx.x;
    const int b = tid >> 3, mi = tid & 7;
#pragma unroll
    for (int ii = 0; ii < 4; ++ii) {
        int mm = mi + ii * 8;
        const float* p = x + ((size_t)b * NN0 + m0 + mm) * 3;
        sh[mm * 96 + b * 3 + 0] = f2bf(p[0]);
        sh[mm * 96 + b * 3 + 1] = f2bf(p[1]);
        sh[mm * 96 + b * 3 + 2] = f2bf(p[2]);
    }
    __syncthreads();
    unsigned int* dst = (unsigned int*)(out + (size_t)m0 * 96);
    const unsigned int* srcp = (const unsigned int*)sh;
    for (int i = tid; i < 32 * 48; i += 256) dst[i] = srcp[i];
}

// ======================= sparse props (bf16) =======================
__global__ __launch_bounds__(256) void sparse_prop16(const int* __restrict__ rowptr, const int* __restrict__ esrc,
                                                     const float* __restrict__ ewt,
                                                     const unsigned short* __restrict__ Tin,
                                                     const unsigned short* __restrict__ Tprev,
                                                     unsigned short* __restrict__ Tout, float s, float t) {
    int g = blockIdx.x * 256 + threadIdx.x;
    int m = g >> 6, lane = g & 63;
    int e0 = rowptr[m], e1 = rowptr[m + 1];
    float acc[8] = {};
    for (int e = e0; e < e1; ++e) {
        float w = ewt[e];
        short8v v = *reinterpret_cast<const short8v*>(Tin + (size_t)esrc[e] * 512 + lane * 8);
#pragma unroll
        for (int j = 0; j < 8; ++j) acc[j] += w * bf2f((unsigned short)v[j]);
    }
    float r[8];
    if (Tprev) {
        short8v pv = *reinterpret_cast<const short8v*>(Tprev + (size_t)m * 512 + lane * 8);
#pragma unroll
        for (int j = 0; j < 8; ++j) r[j] = s * acc[j] + t * bf2f((unsigned short)pv[j]);
    } else {
#pragma unroll
        for (int j = 0; j < 8; ++j) r[j] = s * acc[j];
    }
    uint4 ov;
    ov.x = pk2(r[0], r[1]); ov.y = pk2(r[2], r[3]); ov.z = pk2(r[4], r[5]); ov.w = pk2(r[6], r[7]);
    *reinterpret_cast<uint4*>(Tout + (size_t)m * 512 + lane * 8) = ov;
}

__global__ __launch_bounds__(256) void sparse_prop3(const int* __restrict__ rowptr, const int* __restrict__ esrc,
                                                    const float* __restrict__ ewt,
                                                    const unsigned short* __restrict__ Tin,
                                                    const unsigned short* __restrict__ Tprev,
                                                    unsigned short* __restrict__ Tout, float s, float t) {
    int g = blockIdx.x * 256 + threadIdx.x;
    int m = g / 96, c = g - m * 96;
    int e0 = rowptr[m], e1 = rowptr[m + 1];
    float acc = 0.f;
    for (int e = e0; e < e1; ++e)
        acc += ewt[e] * bf2f(Tin[(size_t)esrc[e] * 96 + c]);
    float v = s * acc;
    if (Tprev) v += t * bf2f(Tprev[(size_t)m * 96 + c]);
    Tout[(size_t)m * 96 + c] = f2bf(v);
}

// ======================= fused sparse epilogue -> bf16 node-major =======================
template <int FIN, int FOUT>
__global__ __launch_bounds__(256) void sparse_epi(const unsigned short* __restrict__ S, size_t slot,
                                                  const float* __restrict__ W, const float* __restrict__ bias,
                                                  unsigned short* __restrict__ out, int relu) {
    __shared__ float Ws[6 * FIN * FOUT];
    for (int i = threadIdx.x; i < 6 * FIN * FOUT; i += 256) Ws[i] = W[i];
    __syncthreads();
    int g = blockIdx.x * 256 + threadIdx.x;   // g = m*32 + b
    int m = g >> 5, b = g & 31;
    float oa[FOUT];
#pragma unroll
    for (int o = 0; o < FOUT; ++o) oa[o] = bias ? bias[o] : 0.f;
    for (int k = 0; k < 6; ++k) {
        const unsigned short* p = S + (size_t)k * slot + (size_t)m * (32 * FIN) + b * FIN;
        float xv[FIN];
        if constexpr (FIN == 16) {
            short8v v0 = *reinterpret_cast<const short8v*>(p);
            short8v v1 = *reinterpret_cast<const short8v*>(p + 8);
#pragma unroll
            for (int f = 0; f < 8; ++f) { xv[f] = bf2f((unsigned short)v0[f]); xv[f + 8] = bf2f((unsigned short)v1[f]); }
        } else {
#pragma unroll
            for (int f = 0; f < FIN; ++f) xv[f] = bf2f(p[f]);
        }
#pragma unroll
        for (int f = 0; f < FIN; ++f)
#pragma unroll
            for (int o = 0; o < FOUT; ++o) oa[o] += xv[f] * Ws[(k * FIN + f) * FOUT + o];
    }
    unsigned short* orow = out + (size_t)m * (32 * FOUT) + b * FOUT;
    unsigned int u[FOUT / 2];
#pragma unroll
    for (int o = 0; o < FOUT / 2; ++o) {
        float a = oa[2 * o], c = oa[2 * o + 1];
        if (relu) { a = fmaxf(a, 0.f); c = fmaxf(c, 0.f); }
        u[o] = pk2(a, c);
    }
#pragma unroll
    for (int q = 0; q < FOUT / 8; ++q)
        reinterpret_cast<uint4*>(orow)[q] = make_uint4(u[4 * q], u[4 * q + 1], u[4 * q + 2], u[4 * q + 3]);
}

// final epilogue: FIN=16 -> 3, fp32 d_out at (b*NN0+m)*3, LDS-staged contiguous writes
__global__ __launch_bounds__(256) void sparse_epi_final(const unsigned short* __restrict__ S, size_t slot,
                                                        const float* __restrict__ W, float* __restrict__ dout) {
    __shared__ float Ws[6 * 16 * 3];
    __shared__ float sh[32 * 24];
    for (int i = threadIdx.x; i < 288; i += 256) Ws[i] = W[i];
    __syncthreads();
    const int tid = threadIdx.x;
    const int mm = tid >> 5, b = tid & 31;
    const int m = blockIdx.x * 8 + mm;
    float o0 = 0.f, o1 = 0.f, o2 = 0.f;
    for (int k = 0; k < 6; ++k) {
        const unsigned short* p = S + (size_t)k * slot + (size_t)m * 512 + b * 16;
        short8v v0 = *reinterpret_cast<const short8v*>(p);
        short8v v1 = *reinterpret_cast<const short8v*>(p + 8);
#pragma unroll
        for (int f = 0; f < 16; ++f) {
            float xf = bf2f((unsigned short)(f < 8 ? v0[f] : v1[f - 8]));
            o0 += xf * Ws[(k * 16 + f) * 3 + 0];
            o1 += xf * Ws[(k * 16 + f) * 3 + 1];
            o2 += xf * Ws[(k * 16 + f) * 3 + 2];
        }
    }
    sh[b * 24 + mm * 3 + 0] = o0;
    sh[b * 24 + mm * 3 + 1] = o1;
    sh[b * 24 + mm * 3 + 2] = o2;
    __syncthreads();
    const size_t base = (size_t)blockIdx.x * 24;
    for (int i = tid; i < 768; i += 256) {
        int b2 = i / 24, r = i - b2 * 24;
        dout[(size_t)b2 * (NN0 * 3) + base + r] = sh[i];
    }
}

// ======================= pools =======================
__device__ __forceinline__ float ldv(const float* p) { return *p; }
__device__ __forceinline__ float ldv(const unsigned short* p) { return bf2f(*p); }

template <typename TI>
__global__ __launch_bounds__(256) void pool_cT(const TI* __restrict__ in, const int* __restrict__ idx,
                                               const float* __restrict__ w, unsigned short* __restrict__ out,
                                               int C, int Mnew) {
    __shared__ float tile[32][33];
    const int m0 = blockIdx.x * 32, c0 = blockIdx.y * 32;
    const int tx = threadIdx.x & 31, ty = threadIdx.x >> 5;
#pragma unroll
    for (int i = 0; i < 4; ++i) {
        int mn = m0 + ty + i * 8;
        const int* ir = idx + mn * 3; const float* wr = w + mn * 3;
        float v = wr[0] * ldv(in + (size_t)ir[0] * C + c0 + tx)
                + wr[1] * ldv(in + (size_t)ir[1] * C + c0 + tx)
                + wr[2] * ldv(in + (size_t)ir[2] * C + c0 + tx);
        tile[ty + i * 8][tx] = v;
    }
    __syncthreads();
#pragma unroll
    for (int i = 0; i < 4; ++i) {
        int c = c0 + ty + i * 8;
        out[(size_t)c * Mnew + m0 + tx] = f2bf(tile[tx][ty + i * 8]);
    }
}

__global__ __launch_bounds__(256) void pool_row16(const unsigned short* __restrict__ in, const int* __restrict__ idx,
                                                  const float* __restrict__ w, unsigned short* __restrict__ out) {
    int g = blockIdx.x * 256 + threadIdx.x;
    int m = g >> 6, lane = g & 63;
    const int* ir = idx + m * 3; const float* wr = w + m * 3;
    short8v a = *reinterpret_cast<const short8v*>(in + (size_t)ir[0] * 512 + lane * 8);
    short8v b = *reinterpret_cast<const short8v*>(in + (size_t)ir[1] * 512 + lane * 8);
    short8v c = *reinterpret_cast<const short8v*>(in + (size_t)ir[2] * 512 + lane * 8);
    float r[8];
#pragma unroll
    for (int j = 0; j < 8; ++j)
        r[j] = wr[0] * bf2f((unsigned short)a[j]) + wr[1] * bf2f((unsigned short)b[j]) + wr[2] * bf2f((unsigned short)c[j]);
    uint4 ov;
    ov.x = pk2(r[0], r[1]); ov.y = pk2(r[2], r[3]); ov.z = pk2(r[4], r[5]); ov.w = pk2(r[6], r[7]);
    *reinterpret_cast<uint4*>(out + (size_t)m * 512 + lane * 8) = ov;
}

__global__ __launch_bounds__(256) void pool_f32(const unsigned short* __restrict__ in, const int* __restrict__ idx,
                                                const float* __restrict__ w, float* __restrict__ out) {
    int g = blockIdx.x * 256 + threadIdx.x;   // 80*1024
    int m = g >> 10, c = g & 1023;
    const int* ir = idx + m * 3; const float* wr = w + m * 3;
    out[g] = wr[0] * bf2f(in[(size_t)ir[0] * 1024 + c])
           + wr[1] * bf2f(in[(size_t)ir[1] * 1024 + c])
           + wr[2] * bf2f(in[(size_t)ir[2] * 1024 + c]);
}

// ======================= MFMA prop GEMM, 2-phase double-buffered ==========================
// Tile BM = MF*64 rows x BN = CF*16 cols. SPLIT: writes bf16 partial Pf[z][C][M].
template <int MF, int CF, bool SPLIT>
__global__ __launch_bounds__(256) void gemm_mfma(const unsigned short* __restrict__ Ab,
                                                 const unsigned short* __restrict__ Xb,
                                                 const unsigned short* __restrict__ Pb,
                                                 unsigned short* __restrict__ Ob,
                                                 unsigned short* __restrict__ Pf,
                                                 int Mn, int KC, float s, float t) {
    constexpr int BM = MF * 64;
    constexpr int BN = CF * 16;
    constexpr int ABYTES = BM * 64 * 2;
    constexpr int XBYTES = BN * 64 * 2;
    constexpr int SEGA = ABYTES / 4096;
    constexpr int SEGX = XBYTES / 4096;
    __shared__ unsigned short As[2][BM * 64];
    __shared__ unsigned short Xs[2][BN * 64];
    const int tid = threadIdx.x;
    const int lane = tid & 63, wid = tid >> 6;
    int lin = blockIdx.y * gridDim.x + blockIdx.x;
    int nwg = gridDim.x * gridDim.y;
    int lin2 = (lin & 7) * (nwg >> 3) + (lin >> 3);
    int by = lin2 / gridDim.x, bx = lin2 - by * gridDim.x;
    const int bm = by * BM, bc = bx * BN;
    const int kbase = SPLIT ? blockIdx.z * KC : 0;
    const int NT = KC / 64;

    const unsigned short* gAsrc[SEGA];
    unsigned int ldsAoff[SEGA];
#pragma unroll
    for (int i = 0; i < SEGA; ++i) {
        int o = (wid * SEGA + i) * 1024 + lane * 16;
        int row = o >> 7;
        int colb = (o & 127) ^ ((row & 7) << 4);
        gAsrc[i] = Ab + (size_t)(bm + row) * Mn + kbase + (colb >> 1);
        ldsAoff[i] = (unsigned int)(wid * SEGA + i) * 1024;
    }
    const unsigned short* gXsrc[SEGX];
    unsigned int ldsXoff[SEGX];
#pragma unroll
    for (int i = 0; i < SEGX; ++i) {
        int o = (wid * SEGX + i) * 1024 + lane * 16;
        int row = o >> 7;
        int colb = (o & 127) ^ ((row & 7) << 4);
        gXsrc[i] = Xb + (size_t)(bc + row) * Mn + kbase + (colb >> 1);
        ldsXoff[i] = (unsigned int)(wid * SEGX + i) * 1024;
    }

    auto STAGE = [&](int buf, int ko) {
#pragma unroll
        for (int i = 0; i < SEGA; ++i)
            __builtin_amdgcn_global_load_lds((const __attribute__((address_space(1))) void*)(gAsrc[i] + ko),
                                             (__attribute__((address_space(3))) void*)((char*)As + buf * ABYTES + ldsAoff[i]),
                                             16, 0, 0);
#pragma unroll
        for (int i = 0; i < SEGX; ++i)
            __builtin_amdgcn_global_load_lds((const __attribute__((address_space(1))) void*)(gXsrc[i] + ko),
                                             (__attribute__((address_space(3))) void*)((char*)Xs + buf * XBYTES + ldsXoff[i]),
                                             16, 0, 0);
    };

    f32x4 acc[MF][CF] = {};

    STAGE(0, 0);
    __syncthreads();
    for (int tt = 0; tt < NT; ++tt) {
        const int cur = tt & 1;
        if (tt + 1 < NT) STAGE(cur ^ 1, (tt + 1) * 64);
        const char* Ac = (const char*)As + cur * ABYTES;
        const char* Xc = (const char*)Xs + cur * XBYTES;
#pragma unroll
        for (int kk = 0; kk < 2; ++kk) {
            short8v a[MF], b[CF];
#pragma unroll
            for (int mf = 0; mf < MF; ++mf) {
                int r = wid * (MF * 16) + mf * 16 + (lane & 15);
                int cb = kk * 64 + ((lane >> 4) * 16);
                int addr = r * 128 + (cb ^ ((r & 7) << 4));
                a[mf] = *reinterpret_cast<const short8v*>(Ac + addr);
            }
#pragma unroll
            for (int cf = 0; cf < CF; ++cf) {
                int r = cf * 16 + (lane & 15);
                int cb = kk * 64 + ((lane >> 4) * 16);
                int addr = r * 128 + (cb ^ ((r & 7) << 4));
                b[cf] = *reinterpret_cast<const short8v*>(Xc + addr);
            }
#pragma unroll
            for (int mf = 0; mf < MF; ++mf)
#pragma unroll
                for (int cf = 0; cf < CF; ++cf)
                    acc[mf][cf] = __builtin_amdgcn_mfma_f32_16x16x32_bf16(a[mf], b[cf], acc[mf][cf], 0, 0, 0);
        }
        __syncthreads();
    }

#pragma unroll
    for (int mf = 0; mf < MF; ++mf) {
        int m0 = bm + wid * (MF * 16) + mf * 16 + ((lane >> 4) * 4);
#pragma unroll
        for (int cf = 0; cf < CF; ++cf) {
            int c = bc + cf * 16 + (lane & 15);
            size_t base = (size_t)c * Mn + m0;
            if constexpr (SPLIT) {
                size_t zbase = (size_t)blockIdx.z * (size_t)(gridDim.x * BN) * (size_t)Mn;
                uint2 ov;
                ov.x = pk2(acc[mf][cf][0], acc[mf][cf][1]);
                ov.y = pk2(acc[mf][cf][2], acc[mf][cf][3]);
                *reinterpret_cast<uint2*>(Pf + zbase + base) = ov;
            } else {
                float v0 = s * acc[mf][cf][0], v1 = s * acc[mf][cf][1];
                float v2 = s * acc[mf][cf][2], v3 = s * acc[mf][cf][3];
                if (Pb) {
                    uint2 pv = *reinterpret_cast<const uint2*>(Pb + base);
                    v0 += t * bf2f((unsigned short)(pv.x & 0xffff));
                    v1 += t * bf2f((unsigned short)(pv.x >> 16));
                    v2 += t * bf2f((unsigned short)(pv.y & 0xffff));
                    v3 += t * bf2f((unsigned short)(pv.y >> 16));
                }
                uint2 ov;
                ov.x = pk2(v0, v1); ov.y = pk2(v2, v3);
                *reinterpret_cast<uint2*>(Ob + base) = ov;
            }
        }
    }
}

// split-K reduce (bf16 partials): Out[g] = bf16( s*sum_ks Pf[ks][g] + t*Prev[g] ), 4 elems/thread
__global__ __launch_bounds__(256) void sk_reduce(const unsigned short* __restrict__ Pf,
                                                 const unsigned short* __restrict__ Prev,
                                                 unsigned short* __restrict__ Out,
                                                 int n4, int KS, float s, float t) {
    int g = blockIdx.x * 256 + threadIdx.x;
    if (g >= n4) return;
    float v0 = 0.f, v1 = 0.f, v2 = 0.f, v3 = 0.f;
    for (int ks = 0; ks < KS; ++ks) {
        uint2 pv = reinterpret_cast<const uint2*>(Pf)[(size_t)ks * n4 + g];
        v0 += bf2f((unsigned short)(pv.x & 0xffff));
        v1 += bf2f((unsigned short)(pv.x >> 16));
        v2 += bf2f((unsigned short)(pv.y & 0xffff));
        v3 += bf2f((unsigned short)(pv.y >> 16));
    }
    v0 *= s; v1 *= s; v2 *= s; v3 *= s;
    if (Prev) {
        uint2 pv = reinterpret_cast<const uint2*>(Prev)[g];
        v0 += t * bf2f((unsigned short)(pv.x & 0xffff));
        v1 += t * bf2f((unsigned short)(pv.x >> 16));
        v2 += t * bf2f((unsigned short)(pv.y & 0xffff));
        v3 += t * bf2f((unsigned short)(pv.y >> 16));
    }
    uint2 ov;
    ov.x = pk2(v0, v1); ov.y = pk2(v2, v3);
    reinterpret_cast<uint2*>(Out)[g] = ov;
}

// ======================= dense fused epilogue -> bf16 [m][32*FOUT] =======================
template <int FIN, int FOUT>
__global__ __launch_bounds__(256) void epi_layer(const unsigned short* __restrict__ Tb, size_t tslot,
                                                 const float* __restrict__ W, const float* __restrict__ bias,
                                                 unsigned short* __restrict__ out, int M) {
    __shared__ float Ws[6 * FIN * FOUT];
    for (int i = threadIdx.x; i < 6 * FIN * FOUT; i += 256) Ws[i] = W[i];
    __syncthreads();
    int g = blockIdx.x * 256 + threadIdx.x;   // g = b*M + m
    int b = g / M, m = g - b * M;
    float oa[FOUT];
#pragma unroll
    for (int o = 0; o < FOUT; ++o) oa[o] = bias[o];
    for (int k = 0; k < 6; ++k) {
        const unsigned short* Tk = Tb + (size_t)k * tslot + (size_t)b * FIN * M + m;
#pragma unroll
        for (int f = 0; f < FIN; ++f) {
            float xf = bf2f(Tk[(size_t)f * M]);
#pragma unroll
            for (int o = 0; o < FOUT; ++o) oa[o] += xf * Ws[(k * FIN + f) * FOUT + o];
        }
    }
    unsigned short* orow = out + (size_t)m * (32 * FOUT) + b * FOUT;
    unsigned int u[FOUT / 2];
#pragma unroll
    for (int o = 0; o < FOUT / 2; ++o)
        u[o] = pk2(fmaxf(oa[2 * o], 0.f), fmaxf(oa[2 * o + 1], 0.f));
#pragma unroll
    for (int q = 0; q < FOUT / 8; ++q)
        reinterpret_cast<uint4*>(orow)[q] = make_uint4(u[4 * q], u[4 * q + 1], u[4 * q + 2], u[4 * q + 3]);
}

// ======================= FCs =======================
__global__ __launch_bounds__(256) void fc_enc_kernel(const float* __restrict__ h, const float* __restrict__ w,
                                                     const float* __restrict__ bias, float* __restrict__ z) {
    __shared__ float sh[256];
    int b = blockIdx.x, o = threadIdx.x & 63, q = threadIdx.x >> 6;
    float acc = 0.f;
    for (int n = q * 20; n < q * 20 + 20; ++n)
#pragma unroll
        for (int f = 0; f < 32; ++f)
            acc += h[((size_t)n * 32 + b) * 32 + f] * w[(size_t)o * 2560 + n * 32 + f];
    sh[threadIdx.x] = acc;
    __syncthreads();
    if (q == 0) z[b * 64 + o] = fmaxf(sh[o] + sh[64 + o] + sh[128 + o] + sh[192 + o] + bias[o], 0.f);
}

__global__ __launch_bounds__(256) void fc_dec_kernel(const float* __restrict__ z, const float* __restrict__ w,
                                                     const float* __restrict__ bias, float* __restrict__ out) {
    int g = blockIdx.x * 256 + threadIdx.x;   // 80*32*32, layout [n][b*32+f]
    if (g >= 80 * 32 * 32) return;
    int f = g % 32; int b = (g / 32) % 32; int n = g / 1024;
    int j = n * 32 + f;
    float acc = bias[j];
    const float* wr = w + (size_t)j * 64;
    const float* zr = z + b * 64;
#pragma unroll
    for (int o = 0; o < 64; ++o) acc += zr[o] * wr[o];
    out[g] = fmaxf(acc, 0.f);
}

// ======================= host orchestration =======================
extern "C" void kernel_launch(void* const* d_in, const int* in_sizes, int n_in,
                              void* d_out, int out_size, void* d_ws, size_t ws_size,
                              hipStream_t stream) {
    (void)n_in; (void)out_size; (void)ws_size;
    const float* x     = (const float*)d_in[0];
    const int*   ei    = (const int*)d_in[1];
    const float* anorm = (const float*)d_in[2];
    const float* adjs[3] = { (const float*)d_in[4], (const float*)d_in[5], (const float*)d_in[6] };
    const int*   dn_idx[4] = { (const int*)d_in[7],  (const int*)d_in[11], (const int*)d_in[15], (const int*)d_in[19] };
    const float* dn_w[4]   = { (const float*)d_in[8],(const float*)d_in[12],(const float*)d_in[16],(const float*)d_in[20] };
    const int*   up_idx[4] = { (const int*)d_in[9],  (const int*)d_in[13], (const int*)d_in[17], (const int*)d_in[21] };
    const float* up_w[4]   = { (const float*)d_in[10],(const float*)d_in[14],(const float*)d_in[18],(const float*)d_in[22] };
    const float* W_enc[4] = { (const float*)d_in[23], (const float*)d_in[25], (const float*)d_in[27], (const float*)d_in[29] };
    const float* b_enc[4] = { (const float*)d_in[24], (const float*)d_in[26], (const float*)d_in[28], (const float*)d_in[30] };
    const float* W_dec[5] = { (const float*)d_in[31], (const float*)d_in[33], (const float*)d_in[35], (const float*)d_in[37], (const float*)d_in[39] };
    const float* b_dec[4] = { (const float*)d_in[32], (const float*)d_in[34], (const float*)d_in[36], (const float*)d_in[38] };
    const float* enc_w = (const float*)d_in[40];
    const float* enc_b = (const float*)d_in[41];
    const float* dec_w = (const float*)d_in[42];
    const float* dec_b = (const float*)d_in[43];
    const int E = in_sizes[2];

    // ---- workspace layout (live-range aliased) ----
    const size_t SLOT16 = (size_t)NN0 * 512;          // ushort elems, 21 MB
    const size_t SLOT3  = (size_t)NN0 * 96;
    unsigned short* S = (unsigned short*)d_ws;        // sparse slots; also split-K partial region (disjoint in time)
    unsigned short* Pf = (unsigned short*)d_ws;       // bf16 partials during dense layers (<= 21 MB)
    unsigned short* Tb = S + 3 * SLOT16;
    unsigned short* HB = Tb + (size_t)6 * 512 * 5120;
    char* p = (char*)(HB + SLOT16);
    unsigned short* adj1b = (unsigned short*)p; p += (size_t)5120 * 5120 * 2;
    unsigned short* adj2b = (unsigned short*)p; p += (size_t)1280 * 1280 * 2;
    unsigned short* adj3b = (unsigned short*)p; p += (size_t)320 * 320 * 2;
    int* rowptr = (int*)p;  p += (NN0 + 4) * sizeof(int);
    int* cnt    = (int*)p;  p += NN0 * sizeof(int);
    int* cursor = (int*)p;  p += NN0 * sizeof(int);
    int* esrc   = (int*)p;  p += (size_t)E * sizeof(int);
    int* eid    = (int*)p;  p += (size_t)E * sizeof(int);
    float* ewt  = (float*)p; p += (size_t)E * sizeof(float);
    float* lat0 = (float*)p; p += 80 * 1024 * sizeof(float);
    float* zb   = (float*)p; p += 32 * 64 * sizeof(float);
    float* lat1 = (float*)p;

    // ---- CSR build (deterministic via per-row sort by edge id) ----
    hipMemsetAsync(cnt, 0, NN0 * sizeof(int), stream);
    count_kernel<<<(E + 255) / 256, 256, 0, stream>>>(ei + E, cnt, E);
    scan_kernel<<<1, 256, 0, stream>>>(cnt, rowptr, cursor, NN0);
    scatter_kernel<<<(E + 255) / 256, 256, 0, stream>>>(ei, ei + E, anorm, cursor, esrc, ewt, eid, E);
    sortrows_kernel<<<(NN0 + 255) / 256, 256, 0, stream>>>(rowptr, esrc, ewt, eid, NN0);

    // ---- adjacency bf16 conversion ----
    convert_flat<<<2048, 256, 0, stream>>>(adjs[0], adj1b, (size_t)5120 * 5120 / 4);
    convert_flat<<<512, 256, 0, stream>>>(adjs[1], adj2b, (size_t)1280 * 1280 / 4);
    convert_flat<<<64, 256, 0, stream>>>(adjs[2], adj3b, (size_t)320 * 320 / 4);

    // ---- helpers ----
    auto dense_layer = [&](const unsigned short* Ab, int M, int FIN, int FOUT,
                           const float* W, const float* bias, unsigned short* HBout) {
        const int C = 32 * FIN;
        const size_t tslot = (size_t)C * M;
        const int CM4 = (int)(tslot / 4);
        for (int k = 1; k < 6; ++k) {
            const unsigned short* Xin = Tb + (size_t)(k - 1) * tslot;
            const unsigned short* Pv  = (k >= 2) ? Tb + (size_t)(k - 2) * tslot : nullptr;
            unsigned short* Oo = Tb + (size_t)k * tslot;
            float s = (k == 1) ? 1.f : 2.f;
            float t = (k == 1) ? 0.f : -1.f;
            if (M == 5120) {
                dim3 gg(C / 64, M / 128, 2);   // BM=128, BN=64, KS=2, KC=2560, 2-phase LDS dbuf
                gemm_mfma<2, 4, true><<<gg, 256, 0, stream>>>(Ab, Xin, nullptr, nullptr, Pf, M, 2560, s, t);
                sk_reduce<<<(CM4 + 255) / 256, 256, 0, stream>>>(Pf, Pv, Oo, CM4, 2, s, t);
            } else if (M == 1280) {
                dim3 gg(C / 64, M / 64, 4);
                gemm_mfma<1, 4, true><<<gg, 256, 0, stream>>>(Ab, Xin, nullptr, nullptr, Pf, M, 320, s, t);
                sk_reduce<<<(CM4 + 255) / 256, 256, 0, stream>>>(Pf, Pv, Oo, CM4, 4, s, t);
            } else {   // M == 320: small, non-split, latency-floor path
                dim3 gg(C / 64, M / 64, 1);
                gemm_mfma<1, 4, false><<<gg, 256, 0, stream>>>(Ab, Xin, Pv, Oo, nullptr, M, M, s, t);
            }
        }
        int blocks = M * 32 / 256;
        if (FIN == 16 && FOUT == 16)      epi_layer<16, 16><<<blocks, 256, 0, stream>>>(Tb, tslot, W, bias, HBout, M);
        else if (FIN == 16 && FOUT == 32) epi_layer<16, 32><<<blocks, 256, 0, stream>>>(Tb, tslot, W, bias, HBout, M);
        else                              epi_layer<32, 16><<<blocks, 256, 0, stream>>>(Tb, tslot, W, bias, HBout, M);
    };
    auto sparse_layer16 = [&](const float* W, const float* bias, int final_relu, unsigned short* out16) {
        for (int k = 1; k < 6; ++k) {
            const unsigned short* Tin = S + (size_t)(k - 1) * SLOT16;
            const unsigned short* Pv  = (k >= 2) ? S + (size_t)(k - 2) * SLOT16 : nullptr;
            sparse_prop16<<<NN0 / 4, 256, 0, stream>>>(rowptr, esrc, ewt, Tin, Pv, S + (size_t)k * SLOT16,
                                                       (k == 1) ? 1.f : 2.f, (k == 1) ? 0.f : -1.f);
        }
        if (out16) sparse_epi<16, 16><<<NN0 * 32 / 256, 256, 0, stream>>>(S, SLOT16, W, bias, out16, final_relu);
        else       sparse_epi_final<<<NN0 / 8, 256, 0, stream>>>(S, SLOT16, W, (float*)d_out);
    };

    // ======================= network =======================
    // --- encoder sparse layer (FIN=3) ---
    xcopy_T<<<NN0 / 32, 256, 0, stream>>>(x, S);
    for (int k = 1; k < 6; ++k) {
        const unsigned short* Tin = S + (size_t)(k - 1) * SLOT3;
        const unsigned short* Pv  = (k >= 2) ? S + (size_t)(k - 2) * SLOT3 : nullptr;
        sparse_prop3<<<NN0 * 96 / 256, 256, 0, stream>>>(rowptr, esrc, ewt, Tin, Pv, S + (size_t)k * SLOT3,
                                                         (k == 1) ? 1.f : 2.f, (k == 1) ? 0.f : -1.f);
    }
    sparse_epi<3, 16><<<NN0 * 32 / 256, 256, 0, stream>>>(S, SLOT3, W_enc[0], b_enc[0], HB, 1);
    // --- dense encoder ---
    { dim3 g(5120 / 32, 512 / 32);  pool_cT<unsigned short><<<g, 256, 0, stream>>>(HB, dn_idx[0], dn_w[0], Tb, 512, 5120); }
    dense_layer(adj1b, 5120, 16, 16, W_enc[1], b_enc[1], HB);
    { dim3 g(1280 / 32, 512 / 32);  pool_cT<unsigned short><<<g, 256, 0, stream>>>(HB, dn_idx[1], dn_w[1], Tb, 512, 1280); }
    dense_layer(adj2b, 1280, 16, 16, W_enc[2], b_enc[2], HB);
    { dim3 g(320 / 32, 512 / 32);   pool_cT<unsigned short><<<g, 256, 0, stream>>>(HB, dn_idx[2], dn_w[2], Tb, 512, 320); }
    dense_layer(adj3b, 320, 16, 32, W_enc[3], b_enc[3], HB);
    pool_f32<<<80 * 1024 / 256, 256, 0, stream>>>(HB, dn_idx[3], dn_w[3], lat0);
    fc_enc_kernel<<<32, 256, 0, stream>>>(lat0, enc_w, enc_b, zb);
    // --- decoder ---
    fc_dec_kernel<<<80 * 32 * 32 / 256, 256, 0, stream>>>(zb, dec_w, dec_b, lat1);
    { dim3 g(320 / 32, 1024 / 32);  pool_cT<float><<<g, 256, 0, stream>>>(lat1, up_idx[3], up_w[3], Tb, 1024, 320); }
    dense_layer(adj3b, 320, 32, 16, W_dec[0], b_dec[0], HB);
    { dim3 g(1280 / 32, 512 / 32);  pool_cT<unsigned short><<<g, 256, 0, stream>>>(HB, up_idx[2], up_w[2], Tb, 512, 1280); }
    dense_layer(adj2b, 1280, 16, 16, W_dec[1], b_dec[1], HB);
    { dim3 g(5120 / 32, 512 / 32);  pool_cT<unsigned short><<<g, 256, 0, stream>>>(HB, up_idx[1], up_w[1], Tb, 512, 5120); }
    dense_layer(adj1b, 5120, 16, 16, W_dec[2], b_dec[2], HB);
    pool_row16<<<NN0 / 4, 256, 0, stream>>>(HB, up_idx[0], up_w[0], S);   // -> S slot0
    // --- decoder sparse layers (FIN=16) ---
    sparse_layer16(W_dec[3], b_dec[3], 1, S);          // epi writes slot0 in-place (owner-thread-safe)
    sparse_layer16(W_dec[4], nullptr, 0, nullptr);     // final -> d_out
}